// Round 1
// baseline (97.527 us; speedup 1.0000x reference)
//
#include <hip/hip_runtime.h>
#include <hip/hip_bf16.h>
#include <math.h>

#define Bb 512
#define Tt 256
#define Cc 384
#define Hh 64
#define N3 192

typedef __attribute__((ext_vector_type(8))) short short8;
typedef __attribute__((ext_vector_type(4))) float float4_;

static __device__ __forceinline__ unsigned short f2bf(float f) {
  union { float f; unsigned u; } v; v.f = f;
  return (unsigned short)((v.u + 0x7FFFu + ((v.u >> 16) & 1u)) >> 16);
}

// ---------------- kernel 0: pack W into transposed bf16 wt[192][384] ----------------
__global__ void wtrans_kernel(const float* __restrict__ wq,
                              const float* __restrict__ wk,
                              const float* __restrict__ wv,
                              unsigned short* __restrict__ wt) {
  int n = blockIdx.x;       // 0..191 output column (q|k|v)
  int k = threadIdx.x;      // 0..383
  const float* w = (n < 64) ? wq : (n < 128) ? wk : wv;
  wt[n * Cc + k] = f2bf(w[k * Hh + (n & 63)]);
}

// ---------------- kernel 1: qkv = x @ [wq|wk|wv]  (bf16 MFMA) ----------------
#define APAD 72
#define WPAD 72

__global__ __launch_bounds__(512) void proj_kernel(
    const float* __restrict__ x, const unsigned short* __restrict__ wt,
    unsigned short* __restrict__ qkv) {
  __shared__ unsigned short a_lds[128 * APAD];
  __shared__ unsigned short w_lds[192 * WPAD];
  const int t = threadIdx.x;
  const int wid = t >> 6, lane = t & 63;
  const int fr = lane & 15, fg = lane >> 4;
  const int wr = wid >> 1, wc = wid & 1;   // 4x2 wave grid: 32 rows x 96 cols each
  const size_t m0 = (size_t)blockIdx.x * 128;

  float4_ acc[2][6];
#pragma unroll
  for (int i = 0; i < 2; i++)
#pragma unroll
    for (int j = 0; j < 6; j++) acc[i][j] = (float4_)0.f;

  for (int k0 = 0; k0 < Cc; k0 += 64) {
    __syncthreads();
    {   // stage A tile 128x64 f32 -> bf16 LDS
      int r = t >> 2, seg = t & 3;
      const float* src = x + (m0 + r) * Cc + k0 + seg * 16;
      float4_ v0 = *(const float4_*)(src);
      float4_ v1 = *(const float4_*)(src + 4);
      float4_ v2 = *(const float4_*)(src + 8);
      float4_ v3 = *(const float4_*)(src + 12);
      short8 w0, w1;
#pragma unroll
      for (int j = 0; j < 4; j++) {
        w0[j]     = (short)f2bf(v0[j]);
        w0[4 + j] = (short)f2bf(v1[j]);
        w1[j]     = (short)f2bf(v2[j]);
        w1[4 + j] = (short)f2bf(v3[j]);
      }
      *(short8*)(&a_lds[r * APAD + seg * 16])     = w0;
      *(short8*)(&a_lds[r * APAD + seg * 16 + 8]) = w1;
    }
#pragma unroll
    for (int i = 0; i < 3; i++) {   // stage W^T tile 192x64 bf16
      int c = t + i * 512;
      int n = c >> 3, seg = c & 7;
      short8 v = *(const short8*)(wt + n * Cc + k0 + seg * 8);
      *(short8*)(&w_lds[n * WPAD + seg * 8]) = v;
    }
    __syncthreads();
#pragma unroll
    for (int kk = 0; kk < 2; kk++) {
      short8 af[2], bfr[6];
#pragma unroll
      for (int mi = 0; mi < 2; mi++)
        af[mi] = *(const short8*)(&a_lds[(wr * 32 + mi * 16 + fr) * APAD + kk * 32 + fg * 8]);
#pragma unroll
      for (int ni = 0; ni < 6; ni++)
        bfr[ni] = *(const short8*)(&w_lds[(wc * 96 + ni * 16 + fr) * WPAD + kk * 32 + fg * 8]);
#pragma unroll
      for (int mi = 0; mi < 2; mi++)
#pragma unroll
        for (int ni = 0; ni < 6; ni++)
          acc[mi][ni] = __builtin_amdgcn_mfma_f32_16x16x32_bf16(af[mi], bfr[ni], acc[mi][ni], 0, 0, 0);
    }
  }
  // epilogue: D layout col=lane&15, row=(lane>>4)*4+reg
#pragma unroll
  for (int mi = 0; mi < 2; mi++)
#pragma unroll
    for (int ni = 0; ni < 6; ni++)
#pragma unroll
      for (int r = 0; r < 4; r++) {
        size_t row = m0 + wr * 32 + mi * 16 + fg * 4 + r;
        int col = wc * 96 + ni * 16 + fr;
        qkv[row * N3 + col] = f2bf(acc[mi][ni][r]);
      }
}

// ---------------- kernel 2: causal flash attention per batch ----------------
#define KPAD 72
#define VTP  264
#define PSTR 40

__global__ __launch_bounds__(256) void attn_kernel(
    const unsigned short* __restrict__ qkv, float* __restrict__ out) {
  __shared__ unsigned short k_lds[Tt * KPAD];      // 36864 B
  __shared__ unsigned short vt_lds[Hh * VTP];      // 33792 B  (V transposed: [h][t])
  __shared__ unsigned short p_lds[4 * 16 * PSTR];  // 5120 B, wave-private P tiles
  const int t = threadIdx.x;
  const int wid = t >> 6, lane = t & 63;
  const int fr = lane & 15, fg = lane >> 4;
  const int b = blockIdx.x;
  const unsigned short* base = qkv + (size_t)b * Tt * N3;

#pragma unroll
  for (int i = 0; i < 8; i++) {
    int c = t + i * 256;
    int row = c >> 3, seg = c & 7;
    short8 kv = *(const short8*)(base + row * N3 + Hh + seg * 8);
    *(short8*)(&k_lds[row * KPAD + seg * 8]) = kv;
    short8 vv = *(const short8*)(base + row * N3 + 2 * Hh + seg * 8);
#pragma unroll
    for (int j = 0; j < 8; j++)
      vt_lds[(seg * 8 + j) * VTP + row] = (unsigned short)vv[j];
  }
  __syncthreads();

  const float SC  = 0.05103103630798288f;   // 384^-0.5
  const float L2E = 1.4426950408889634f;

  int qts[4] = { wid, 7 - wid, 8 + wid, 15 - wid };  // balanced causal work
#pragma unroll 1
  for (int qi = 0; qi < 4; qi++) {
    int qt = qts[qi];
    short8 aq[2];
#pragma unroll
    for (int kk = 0; kk < 2; kk++)
      aq[kk] = *(const short8*)(base + (qt * 16 + fr) * N3 + kk * 32 + fg * 8);
    float4_ o[4] = {(float4_)0.f, (float4_)0.f, (float4_)0.f, (float4_)0.f};
    float m[4], lsum[4];
#pragma unroll
    for (int r = 0; r < 4; r++) { m[r] = -1e30f; lsum[r] = 0.f; }
    int ktmax = (qt * 16 + 15) >> 5;
    for (int kt = 0; kt <= ktmax; kt++) {
      float4_ s0 = (float4_)0.f, s1 = (float4_)0.f;
#pragma unroll
      for (int kk = 0; kk < 2; kk++) {
        short8 b0 = *(const short8*)(&k_lds[(kt * 32 + fr) * KPAD + kk * 32 + fg * 8]);
        short8 b1 = *(const short8*)(&k_lds[(kt * 32 + 16 + fr) * KPAD + kk * 32 + fg * 8]);
        s0 = __builtin_amdgcn_mfma_f32_16x16x32_bf16(aq[kk], b0, s0, 0, 0, 0);
        s1 = __builtin_amdgcn_mfma_f32_16x16x32_bf16(aq[kk], b1, s1, 0, 0, 0);
      }
      bool edge = (kt == ktmax);
#pragma unroll
      for (int r = 0; r < 4; r++) {
        int qg = qt * 16 + fg * 4 + r;
        float v0 = s0[r] * SC, v1 = s1[r] * SC;
        if (edge) {
          if (kt * 32 + fr > qg)      v0 = -1e30f;
          if (kt * 32 + 16 + fr > qg) v1 = -1e30f;
        }
        float mx = fmaxf(v0, v1);
#pragma unroll
        for (int d = 1; d < 16; d <<= 1) mx = fmaxf(mx, __shfl_xor(mx, d));
        float mn = fmaxf(m[r], mx);
        float sc = exp2f((m[r] - mn) * L2E);
        float p0 = exp2f((v0 - mn) * L2E);
        float p1 = exp2f((v1 - mn) * L2E);
        m[r] = mn;
        float ps = p0 + p1;
#pragma unroll
        for (int d = 1; d < 16; d <<= 1) ps += __shfl_xor(ps, d);
        lsum[r] = lsum[r] * sc + ps;
#pragma unroll
        for (int nt = 0; nt < 4; nt++) o[nt][r] *= sc;
        int prow = fg * 4 + r;
        p_lds[wid * 16 * PSTR + prow * PSTR + fr]      = f2bf(p0);
        p_lds[wid * 16 * PSTR + prow * PSTR + 16 + fr] = f2bf(p1);
      }
      asm volatile("s_waitcnt lgkmcnt(0)" ::: "memory");
      __builtin_amdgcn_sched_barrier(0);
      short8 pa = *(const short8*)(&p_lds[wid * 16 * PSTR + fr * PSTR + fg * 8]);
#pragma unroll
      for (int nt = 0; nt < 4; nt++) {
        short8 bv = *(const short8*)(&vt_lds[(nt * 16 + fr) * VTP + kt * 32 + fg * 8]);
        o[nt] = __builtin_amdgcn_mfma_f32_16x16x32_bf16(pa, bv, o[nt], 0, 0, 0);
      }
    }
#pragma unroll
    for (int nt = 0; nt < 4; nt++)
#pragma unroll
      for (int r = 0; r < 4; r++) {
        int row = qt * 16 + fg * 4 + r;
        out[((size_t)b * Tt + row) * Hh + nt * 16 + fr] = o[nt][r] / lsum[r];
      }
  }
}

extern "C" void kernel_launch(void* const* d_in, const int* in_sizes, int n_in,
                              void* d_out, int out_size, void* d_ws, size_t ws_size,
                              hipStream_t stream) {
  const float* x  = (const float*)d_in[0];
  const float* wq = (const float*)d_in[1];
  const float* wk = (const float*)d_in[2];
  const float* wv = (const float*)d_in[3];
  unsigned short* wt  = (unsigned short*)d_ws;
  unsigned short* qkv = wt + 192 * 384;   // 147456 B then 50.3 MB of qkv bf16
  float* out = (float*)d_out;

  hipLaunchKernelGGL(wtrans_kernel, dim3(192),  dim3(384), 0, stream, wq, wk, wv, wt);
  hipLaunchKernelGGL(proj_kernel,   dim3(1024), dim3(512), 0, stream, x, wt, qkv);
  hipLaunchKernelGGL(attn_kernel,   dim3(Bb),   dim3(256), 0, stream, qkv, out);
}